// Round 6
// baseline (454.502 us; speedup 1.0000x reference)
//
#include <hip/hip_runtime.h>

#define B_   512
#define D_   256
#define P_   196
#define N2B  1024   // 2B rows in Z

// Z is pre-scaled by CSCALE: CSCALE^2 = (1/T)*log2(e) = 2.8853900818 (T=0.5),
// so MFMA acc = 2.885*dot and exp(2*dot) = exp2f(acc); true sim = acc*ln2.
#define CSCALE 1.69864364f
#define LN2    0.69314718f
#define T2L    2.8853900817779268f   // 2*log2(e)

typedef __attribute__((ext_vector_type(8))) short short8;
typedef __attribute__((ext_vector_type(4))) float f32x4;
typedef unsigned int u32;

#define LDSP(x) ((__attribute__((address_space(3))) u32*)(x))
#define GLBP(x) ((const __attribute__((address_space(1))) u32*)(x))

// Static device buffers. Every slot is rewritten on every call (no init needed).
__device__ unsigned short g_Z[(size_t)P_ * N2B * D_];   // ~103 MB bf16, [p][row][d], pre-scaled
__device__ float g_rowps[(size_t)P_ * 8 * N2B];         // row exp-sum partials [p][slot][row]
__device__ float g_pp2[P_ * 4];                         // partner-sim per partner tile (x2)
__device__ float g_mApart[128 * P_];                    // meanA partials (128 slices)
__device__ float g_dpart[(size_t)B_ * 4 * P_];          // lf denom partials [(b*4+dq)][p]
__device__ float g_partials[P_];

// upper-triangle tile enumeration (36 tiles of the 8x8 tile grid)
static __device__ const unsigned char TROW36[36] = {
  0,0,0,0,0,0,0,0, 1,1,1,1,1,1,1, 2,2,2,2,2,2, 3,3,3,3,3, 4,4,4,4, 5,5,5, 6,6, 7};
static __device__ const unsigned char TCOL36[36] = {
  0,1,2,3,4,5,6,7, 1,2,3,4,5,6,7, 2,3,4,5,6,7, 3,4,5,6,7, 4,5,6,7, 5,6,7, 6,7, 7};

static __device__ inline unsigned short f2bf(float f) {
    union { float f; unsigned int u; } v; v.f = f;
    unsigned int u = v.u;
    return (unsigned short)((u + 0x7fffu + ((u >> 16) & 1u)) >> 16);  // RNE
}
static __device__ inline float bf2f(unsigned short h) {
    union { unsigned int u; float f; } v; v.u = ((unsigned int)h) << 16;
    return v.f;
}
static __device__ inline float wave_sum(float v) {
    for (int off = 32; off > 0; off >>= 1) v += __shfl_xor(v, off, 64);
    return v;
}

// ---- P1: grid-fused streaming pass, all branches block-uniform, tiny LDS.
// blocks 0..127   : gchain (serial softmax chain -> Z rows 512..1023) — launched first
// blocks 128..255 : meanA partials (32 att rows each)
// blocks 256..2303: lf denominators: (b, dq) chunk = [64 d][196 p], coalesced stream,
//                   per-wave LDS f32 atomics, partial per (b,dq,p).
__global__ __launch_bounds__(256) void prep1_kernel(const float* __restrict__ gf,
                                                    const float* __restrict__ att,
                                                    const float* __restrict__ outs) {
    __shared__ float ssw[4][200];
    int blk = blockIdx.x, t = threadIdx.x;

    if (blk < 128) {
        int wv = t >> 6, lane = t & 63;
        int b = blk * 4 + wv;
        float4 g = ((const float4*)(gf + (size_t)b * D_))[lane];
        for (int p = 0; p < P_; ++p) {
            float e0 = __expf(g.x), e1 = __expf(g.y), e2 = __expf(g.z), e3 = __expf(g.w);
            float s1 = e0 + e1 + e2 + e3;
            float s2 = e0 * e0 + e1 * e1 + e2 * e2 + e3 * e3;
#pragma unroll
            for (int off = 32; off > 0; off >>= 1) {
                s1 += __shfl_xor(s1, off, 64);
                s2 += __shfl_xor(s2, off, 64);
            }
            float isq = rsqrtf(s2) * CSCALE;   // normalized + pre-scaled
            ushort4 o;
            o.x = f2bf(e0 * isq); o.y = f2bf(e1 * isq); o.z = f2bf(e2 * isq); o.w = f2bf(e3 * isq);
            ((ushort4*)(g_Z + ((size_t)p * N2B + B_ + b) * D_))[lane] = o;
            float inv = 1.0f / s1;             // next iteration's g = softmax
            g.x = e0 * inv; g.y = e1 * inv; g.z = e2 * inv; g.w = e3 * inv;
        }
    } else if (blk < 256) {
        int bk = blk - 128;                    // 128 blocks x 32 rows of att[4096][196]
        if (t < P_) {
            float acc = 0.0f;
            const float* base = att + (size_t)bk * 32 * P_ + t;
            for (int r = 0; r < 32; ++r) acc += base[(size_t)r * P_];
            g_mApart[bk * P_ + t] = acc;
        }
    } else {
        int id = blk - 256;                    // 0..2047
        int b = id >> 2, dq = id & 3;          // 64-d chunk
        int wv = t >> 6;
        for (int i = t; i < 800; i += 256) ((float*)ssw)[i] = 0.0f;
        __syncthreads();
        const float4* src4 = (const float4*)(outs + (size_t)b * (D_ * P_) + dq * (64 * P_));
        for (int idx = t; idx < 3136; idx += 256) {
            float4 v = src4[idx];
            int c4 = (idx % 49) * 4;
            atomicAdd(&ssw[wv][c4 + 0], exp2f(v.x * T2L));
            atomicAdd(&ssw[wv][c4 + 1], exp2f(v.y * T2L));
            atomicAdd(&ssw[wv][c4 + 2], exp2f(v.z * T2L));
            atomicAdd(&ssw[wv][c4 + 3], exp2f(v.w * T2L));
        }
        __syncthreads();
        if (t < P_)
            g_dpart[(size_t)id * P_ + t] = ssw[0][t] + ssw[1][t] + ssw[2][t] + ssw[3][t];
    }
}

// ---- P2: per (b, d-half): re-read [128 d][196 p] chunk (L3-hot), LDS transpose,
// apply q = exp(v) * rsqrt(denom) * CSCALE, write bf16 Z rows 0..511.
__global__ __launch_bounds__(256) void prep2_kernel(const float* __restrict__ outs) {
    __shared__ unsigned short vt[128 * 202];   // 51.7 KB -> 3 blocks/CU
    __shared__ float ss[P_];
    int blk = blockIdx.x, t = threadIdx.x;
    int b = blk >> 1, dh = blk & 1;
    const float4* src4 = (const float4*)(outs + (size_t)b * (D_ * P_) + dh * (128 * P_));
    for (int idx = t; idx < 6272; idx += 256) {
        int d = idx / 49, c = idx - d * 49;
        float4 v = src4[idx];
        unsigned short* dst = vt + d * 202 + c * 4;
        ushort2 a, bb;
        a.x = f2bf(v.x); a.y = f2bf(v.y); bb.x = f2bf(v.z); bb.y = f2bf(v.w);
        *(ushort2*)dst = a; *(ushort2*)(dst + 2) = bb;
    }
    if (t < P_) {
        const float* dp = g_dpart + (size_t)(b * 4) * P_ + t;
        float s = dp[0] + dp[P_] + dp[2 * P_] + dp[3 * P_];
        ss[t] = rsqrtf(s) * CSCALE;
    }
    __syncthreads();
    int w = t >> 6, l = t & 63;
    for (int i = 0; i < 49; ++i) {
        int p = w * 49 + i;
        float v0 = bf2f(vt[(2 * l) * 202 + p]);
        float v1 = bf2f(vt[(2 * l + 1) * 202 + p]);
        float sc = ss[p];
        ushort2 o;
        o.x = f2bf(__expf(v0) * sc);
        o.y = f2bf(__expf(v1) * sc);
        *(ushort2*)(g_Z + ((size_t)p * N2B + b) * D_ + dh * 128 + 2 * l) = o;
    }
}

// ---- sim epilogue, specialized per tile type (block-uniform dispatch).
// MODE 0 plain, 1 diag (mask local diagonal; pcs kept for the sym-reconstruct wave),
// 2 partner (collect sim on diag)
template<int MODE>
static __device__ inline void do_epi(const f32x4 acc[4][4], float psum[4][4], float pcs[4],
                                     float& pp, int wdiag, int lr, int r4) {
#pragma unroll
    for (int i = 0; i < 4; ++i) {
#pragma unroll
        for (int j = 0; j < 4; ++j) {
#pragma unroll
            for (int r = 0; r < 4; ++r) {
                float a = acc[i][j][r];
                float e = exp2f(a);                    // = exp(2*dot), scale pre-folded
                if (MODE == 1) {
                    if (wdiag && i == j) e = (r4 + r == lr) ? 0.0f : e;
                }
                psum[i][r] += e;
                pcs[j] += e;
                if (MODE == 2) {
                    if (wdiag && i == j && (r4 + r == lr)) pp += a * LN2;  // true sim
                }
            }
        }
    }
}

// ---- Kernel C: symmetric tiled GEMM, one upper-triangle 128x128 tile per block.
// DIAG tiles: skip B staging (B==A) and skip the lower-left wave (reconstructed
// from the upper-right wave's col-sums by symmetry).
__global__ __launch_bounds__(256, 4) void sim_kernel() {
    __shared__ __align__(16) unsigned short As[128 * 64];  // [row][k] bf16, swizzled kbytes
    __shared__ __align__(16) unsigned short Bs[128 * 64];
    __shared__ float combuf[512];                          // rowbuf[2][128] + colbuf[2][128]
    __shared__ float ppred[4];

    int lin0 = blockIdx.x;                 // 7056 = 8 * 882
    int xcd = lin0 & 7, slot = lin0 >> 3;  // co-locate each p's tiles on one XCD
    int lin = xcd * 882 + slot;
    int p = lin / 36;
    int t36 = lin - p * 36;
    int trow = TROW36[t36], tcol = TCOL36[t36];
    bool DIAG = (trow == tcol);
    bool PART = (trow < 4) && (tcol == trow + 4);

    int tid = threadIdx.x;
    int wv = tid >> 6, lane = tid & 63;
    int wr = wv >> 1, wc = wv & 1;
    int lr = lane & 15;
    int lk16 = (lane >> 4) * 16;           // byte offset of k-chunk in 128B row
    bool skipw = DIAG && (wv == 2);        // lower-left wave of a diagonal tile

    const char* zb = (const char*)g_Z + (size_t)p * ((size_t)N2B * D_ * 2);
    const char* gA = zb + (size_t)trow * (128 * 512);
    const char* gB = zb + (size_t)tcol * (128 * 512);
    // inverse-swizzled per-lane source offset: lane l -> row l>>3, kbyte ((l&7)^(l>>3))*16
    int lsub = (lane >> 3) * 512 + (((lane & 7) ^ (lane >> 3)) << 4);

    f32x4 acc[4][4];
#pragma unroll
    for (int i = 0; i < 4; ++i)
#pragma unroll
        for (int j = 0; j < 4; ++j)
            acc[i][j] = (f32x4){0.0f, 0.0f, 0.0f, 0.0f};

    const char* BsR = DIAG ? (const char*)As : (const char*)Bs;

    for (int ko = 0; ko < 4; ++ko) {
#pragma unroll
        for (int it = 0; it < 4; ++it) {
            int s = it * 4 + wv;
            int go = s * 4096 + ko * 128 + lsub;
            __builtin_amdgcn_global_load_lds(GLBP(gA + go), LDSP((char*)As + s * 1024), 16, 0, 0);
            if (!DIAG)
                __builtin_amdgcn_global_load_lds(GLBP(gB + go), LDSP((char*)Bs + s * 1024), 16, 0, 0);
        }
        __syncthreads();   // vmcnt(0) drain + barrier
        if (!skipw) {
#pragma unroll
            for (int ks = 0; ks < 2; ++ks) {
                int kswz = (ks * 64 + lk16) ^ ((lr & 7) << 4);   // swizzled read kbyte
                short8 a[4], b[4];
#pragma unroll
                for (int i = 0; i < 4; ++i) {
                    a[i] = *(const short8*)((const char*)As + (wr * 64 + i * 16 + lr) * 128 + kswz);
                    b[i] = *(const short8*)(BsR + (wc * 64 + i * 16 + lr) * 128 + kswz);
                }
#pragma unroll
                for (int i = 0; i < 4; ++i)
#pragma unroll
                    for (int j = 0; j < 4; ++j)
                        acc[i][j] = __builtin_amdgcn_mfma_f32_16x16x32_bf16(a[i], b[j], acc[i][j], 0, 0, 0);
            }
        }
        __syncthreads();
    }

    int wdiag = (wr == wc);
    int r4 = (lane >> 4) * 4;
    float psum[4][4];
    float pcs[4] = {0.0f, 0.0f, 0.0f, 0.0f};
    float pp = 0.0f;
#pragma unroll
    for (int i = 0; i < 4; ++i)
#pragma unroll
        for (int r = 0; r < 4; ++r) psum[i][r] = 0.0f;

    if (!skipw) {
        if (DIAG)      do_epi<1>(acc, psum, pcs, pp, wdiag, lr, r4);
        else if (PART) do_epi<2>(acc, psum, pcs, pp, wdiag, lr, r4);
        else           do_epi<0>(acc, psum, pcs, pp, wdiag, lr, r4);
    }

    float* rowbuf = combuf;         // [wc][128]
    float* colbuf = combuf + 256;   // [wr][128]
    if (!skipw) {
#pragma unroll
        for (int i = 0; i < 4; ++i)
#pragma unroll
            for (int r = 0; r < 4; ++r) {
                float ps = psum[i][r];
                ps += __shfl_xor(ps, 1, 64);
                ps += __shfl_xor(ps, 2, 64);
                ps += __shfl_xor(ps, 4, 64);
                ps += __shfl_xor(ps, 8, 64);
                if (lr == 0) rowbuf[wc * 128 + wr * 64 + i * 16 + r4 + r] = ps;
            }
    }
    if (!DIAG) {
#pragma unroll
        for (int j = 0; j < 4; ++j) {
            float pc = pcs[j];
            pc += __shfl_xor(pc, 16, 64);
            pc += __shfl_xor(pc, 32, 64);
            if (lane < 16) colbuf[wr * 128 + wc * 64 + j * 16 + lane] = pc;
        }
    } else if (wv == 1) {
        // wave (0,1): its col-sums == row-sums of rows 64..127 over cols 0..63
        // (the skipped wave's contribution) -> rowbuf slot [wc=0][64..127]
#pragma unroll
        for (int j = 0; j < 4; ++j) {
            float pc = pcs[j];
            pc += __shfl_xor(pc, 16, 64);
            pc += __shfl_xor(pc, 32, 64);
            if (lane < 16) rowbuf[64 + j * 16 + lane] = pc;
        }
    }
    if (PART) {
        float pw = wave_sum(pp);
        if (lane == 0) ppred[wv] = pw;
    }
    __syncthreads();

    // row-part -> slot tcol (rows trow*128..); col-part -> slot trow (rows tcol*128..)
    if (tid < 128) {
        float v = rowbuf[tid] + rowbuf[128 + tid];
        g_rowps[((size_t)p * 8 + tcol) * N2B + trow * 128 + tid] = v;
    } else if (!DIAG) {
        int x = tid - 128;
        float v = colbuf[x] + colbuf[128 + x];
        g_rowps[((size_t)p * 8 + trow) * N2B + tcol * 128 + x] = v;
    }
    if (PART && tid == 0)
        g_pp2[p * 4 + trow] = 2.0f * (ppred[0] + ppred[1] + ppred[2] + ppred[3]);
}

// ---- Kernel R: per p: sum_rows log(sum of 8 slots) - partner, times meanA
__global__ __launch_bounds__(256) void rowreduce_kernel() {
    int p = blockIdx.x, t = threadIdx.x;
    const float* base = g_rowps + (size_t)p * 8 * N2B;
    float s = 0.0f;
    for (int r = t; r < N2B; r += 256) {
        float S = 0.0f;
#pragma unroll
        for (int k = 0; k < 8; ++k) S += base[(size_t)k * N2B + r];
        s += __logf(S);
    }
    s = wave_sum(s);
    __shared__ float red[4];
    int wv = t >> 6, lane = t & 63;
    if (lane == 0) red[wv] = s;
    __syncthreads();
    if (t == 0) {
        float tot = red[0] + red[1] + red[2] + red[3];
        float pp = g_pp2[p * 4 + 0] + g_pp2[p * 4 + 1] + g_pp2[p * 4 + 2] + g_pp2[p * 4 + 3];
        float ma = 0.0f;
        for (int k = 0; k < 128; ++k) ma += g_mApart[k * P_ + p];
        g_partials[p] = (tot - pp) * (ma * (1.0f / B_));
    }
}

// ---- Kernel F: out = sum_p partials[p] / (2B * P)
__global__ __launch_bounds__(256) void final_kernel(float* __restrict__ out) {
    int t = threadIdx.x;
    float s = (t < P_) ? g_partials[t] : 0.0f;
    s = wave_sum(s);
    __shared__ float red[4];
    int wv = t >> 6, lane = t & 63;
    if (lane == 0) red[wv] = s;
    __syncthreads();
    if (t == 0) out[0] = (red[0] + red[1] + red[2] + red[3]) * (1.0f / ((float)N2B * (float)P_));
}

extern "C" void kernel_launch(void* const* d_in, const int* in_sizes, int n_in,
                              void* d_out, int out_size, void* d_ws, size_t ws_size,
                              hipStream_t stream) {
    const float* gf   = (const float*)d_in[0];   // [512, 256]
    const float* att  = (const float*)d_in[1];   // [512, 8, 14, 14]
    const float* outs = (const float*)d_in[2];   // [512, 256, 14, 14]
    float* out = (float*)d_out;

    hipLaunchKernelGGL(prep1_kernel, dim3(2304), dim3(256), 0, stream, gf, att, outs);
    hipLaunchKernelGGL(prep2_kernel, dim3(B_ * 2), dim3(256), 0, stream, outs);
    hipLaunchKernelGGL(sim_kernel, dim3(P_ * 36), dim3(256), 0, stream);
    hipLaunchKernelGGL(rowreduce_kernel, dim3(P_), dim3(256), 0, stream);
    hipLaunchKernelGGL(final_kernel, dim3(1), dim3(256), 0, stream, out);
}

// Round 7
// 353.819 us; speedup vs baseline: 1.2846x; 1.2846x over previous
//
#include <hip/hip_runtime.h>

#define B_   512
#define D_   256
#define P_   196
#define N2B  1024   // 2B rows in Z

// Z is pre-scaled by CSCALE: CSCALE^2 = (1/T)*log2(e) = 2.8853900818 (T=0.5),
// so MFMA acc = 2.885*dot and exp(2*dot) = exp2f(acc); true sim = acc*ln2.
#define CSCALE 1.69864364f
#define LN2    0.69314718f
#define T2L    2.8853900817779268f   // 2*log2(e)

typedef __attribute__((ext_vector_type(8))) short short8;
typedef __attribute__((ext_vector_type(4))) float f32x4;
typedef unsigned int u32;

#define LDSP(x) ((__attribute__((address_space(3))) u32*)(x))
#define GLBP(x) ((const __attribute__((address_space(1))) u32*)(x))

// Static device buffers. Every slot is rewritten on every call (no init needed).
__device__ unsigned short g_Z[(size_t)P_ * N2B * D_];   // ~103 MB bf16, [p][row][d], pre-scaled
__device__ float g_rowps[(size_t)P_ * 8 * N2B];         // row exp-sum partials [p][slot][row]
__device__ float g_pp2[P_ * 4];                         // partner-sim per partner tile (x2)
__device__ float g_mApart[128 * P_];                    // meanA partials (128 slices)
__device__ float g_dscale[(size_t)B_ * P_];             // lf scale = rsqrt(denom)*CSCALE
__device__ float g_partials[P_];

// upper-triangle tile enumeration (36 tiles of the 8x8 tile grid)
static __device__ const unsigned char TROW36[36] = {
  0,0,0,0,0,0,0,0, 1,1,1,1,1,1,1, 2,2,2,2,2,2, 3,3,3,3,3, 4,4,4,4, 5,5,5, 6,6, 7};
static __device__ const unsigned char TCOL36[36] = {
  0,1,2,3,4,5,6,7, 1,2,3,4,5,6,7, 2,3,4,5,6,7, 3,4,5,6,7, 4,5,6,7, 5,6,7, 6,7, 7};

static __device__ inline unsigned short f2bf(float f) {
    union { float f; unsigned int u; } v; v.f = f;
    unsigned int u = v.u;
    return (unsigned short)((u + 0x7fffu + ((u >> 16) & 1u)) >> 16);  // RNE
}
static __device__ inline float bf2f(unsigned short h) {
    union { unsigned int u; float f; } v; v.u = ((unsigned int)h) << 16;
    return v.f;
}
static __device__ inline float wave_sum(float v) {
    for (int off = 32; off > 0; off >>= 1) v += __shfl_xor(v, off, 64);
    return v;
}

// VALU-speed reduction across a 16-lane DPP row (4 dependent adds, ~4cyc each,
// vs 4-6 DS-shfl levels at ~120cyc dependent latency).
template<int CTRL>
static __device__ inline float dpp_add_step(float v) {
    int t = __builtin_amdgcn_update_dpp(0, __float_as_int(v), CTRL, 0xf, 0xf, true);
    return v + __int_as_float(t);
}
static __device__ inline float row16_sum(float v) {
    v = dpp_add_step<0xB1>(v);    // quad_perm xor1
    v = dpp_add_step<0x4E>(v);    // quad_perm xor2
    v = dpp_add_step<0x141>(v);   // row_half_mirror (pairs across quads)
    v = dpp_add_step<0x140>(v);   // row_mirror (pairs across octets)
    return v;                     // all 16 lanes hold the 16-lane sum
}

// ---- P12: grid-fused streaming pass, block-uniform branches, no big LDS.
// blocks 0..31    : gchain, DPP-reduced. 16 lanes/row, 16 elems/lane, 16 rows/block.
// blocks 32..543  : lf denominators: block=b, thread=p, 256 coalesced loads, write scale.
// blocks 544..671 : meanA partials (32 att rows each).
__global__ __launch_bounds__(256) void prep12_kernel(const float* __restrict__ gf,
                                                     const float* __restrict__ att,
                                                     const float* __restrict__ outs) {
    int blk = blockIdx.x, t = threadIdx.x;

    if (blk < 32) {
        int wv = t >> 6, lane = t & 63;
        int rw = lane >> 4, lr = lane & 15;
        int b = blk * 16 + wv * 4 + rw;
        const float4* gfr = (const float4*)(gf + (size_t)b * D_);
        float g[16], e[16];
        {
            float4 q0 = gfr[lr], q1 = gfr[lr + 16], q2 = gfr[lr + 32], q3 = gfr[lr + 48];
            g[0]=q0.x; g[1]=q0.y; g[2]=q0.z; g[3]=q0.w;
            g[4]=q1.x; g[5]=q1.y; g[6]=q1.z; g[7]=q1.w;
            g[8]=q2.x; g[9]=q2.y; g[10]=q2.z; g[11]=q2.w;
            g[12]=q3.x; g[13]=q3.y; g[14]=q3.z; g[15]=q3.w;
        }
        for (int p = 0; p < P_; ++p) {
            float s1 = 0.0f, s2 = 0.0f;
#pragma unroll
            for (int i = 0; i < 16; ++i) {
                e[i] = __expf(g[i]);
                s1 += e[i];
                s2 = fmaf(e[i], e[i], s2);
            }
            s1 = row16_sum(s1);
            s2 = row16_sum(s2);
            float isq = rsqrtf(s2) * CSCALE;
            float inv = 1.0f / s1;
            unsigned short* zr = g_Z + ((size_t)p * N2B + B_ + b) * D_;
#pragma unroll
            for (int c = 0; c < 4; ++c) {
                ushort4 o;
                o.x = f2bf(e[c * 4 + 0] * isq);
                o.y = f2bf(e[c * 4 + 1] * isq);
                o.z = f2bf(e[c * 4 + 2] * isq);
                o.w = f2bf(e[c * 4 + 3] * isq);
                *(ushort4*)(zr + c * 64 + lr * 4) = o;
            }
#pragma unroll
            for (int i = 0; i < 16; ++i) g[i] = e[i] * inv;
        }
    } else if (blk < 544) {
        int b = blk - 32;
        if (t < P_) {
            const float* src = outs + (size_t)b * (D_ * P_) + t;
            float s = 0.0f;
#pragma unroll 8
            for (int d = 0; d < 256; ++d) s += exp2f(src[(size_t)d * P_] * T2L);
            g_dscale[(size_t)b * P_ + t] = rsqrtf(s) * CSCALE;
        }
    } else {
        int bk = blk - 544;                    // 128 blocks x 32 rows of att[4096][196]
        if (t < P_) {
            float acc = 0.0f;
            const float* base = att + (size_t)bk * 32 * P_ + t;
            for (int r = 0; r < 32; ++r) acc += base[(size_t)r * P_];
            g_mApart[bk * P_ + t] = acc;
        }
    }
}

// ---- P2: per (b, d-half): re-read [128 d][196 p] chunk (L3-hot), LDS transpose,
// apply q = exp(v) * scale, write bf16 Z rows 0..511.
__global__ __launch_bounds__(256) void prep2_kernel(const float* __restrict__ outs) {
    __shared__ unsigned short vt[128 * 202];   // 51.7 KB -> 3 blocks/CU
    __shared__ float ss[P_];
    int blk = blockIdx.x, t = threadIdx.x;
    int b = blk >> 1, dh = blk & 1;
    const float4* src4 = (const float4*)(outs + (size_t)b * (D_ * P_) + dh * (128 * P_));
    for (int idx = t; idx < 6272; idx += 256) {
        int d = idx / 49, c = idx - d * 49;
        float4 v = src4[idx];
        unsigned short* dst = vt + d * 202 + c * 4;
        ushort2 a, bb;
        a.x = f2bf(v.x); a.y = f2bf(v.y); bb.x = f2bf(v.z); bb.y = f2bf(v.w);
        *(ushort2*)dst = a; *(ushort2*)(dst + 2) = bb;
    }
    if (t < P_) ss[t] = g_dscale[(size_t)b * P_ + t];
    __syncthreads();
    int w = t >> 6, l = t & 63;
    for (int i = 0; i < 49; ++i) {
        int p = w * 49 + i;
        float v0 = bf2f(vt[(2 * l) * 202 + p]);
        float v1 = bf2f(vt[(2 * l + 1) * 202 + p]);
        float sc = ss[p];
        ushort2 o;
        o.x = f2bf(__expf(v0) * sc);
        o.y = f2bf(__expf(v1) * sc);
        *(ushort2*)(g_Z + ((size_t)p * N2B + b) * D_ + dh * 128 + 2 * l) = o;
    }
}

// ---- sim epilogue, specialized per tile type (block-uniform dispatch).
// MODE 0 plain, 1 diag (mask local diagonal; pcs kept for the sym-reconstruct wave),
// 2 partner (collect sim on diag)
template<int MODE>
static __device__ inline void do_epi(const f32x4 acc[4][4], float psum[4][4], float pcs[4],
                                     float& pp, int wdiag, int lr, int r4) {
#pragma unroll
    for (int i = 0; i < 4; ++i) {
#pragma unroll
        for (int j = 0; j < 4; ++j) {
#pragma unroll
            for (int r = 0; r < 4; ++r) {
                float a = acc[i][j][r];
                float e = exp2f(a);                    // = exp(2*dot), scale pre-folded
                if (MODE == 1) {
                    if (wdiag && i == j) e = (r4 + r == lr) ? 0.0f : e;
                }
                psum[i][r] += e;
                pcs[j] += e;
                if (MODE == 2) {
                    if (wdiag && i == j && (r4 + r == lr)) pp += a * LN2;  // true sim
                }
            }
        }
    }
}

// ---- Kernel C: symmetric tiled GEMM, one upper-triangle 128x128 tile per block.
// DIAG tiles: skip B staging (B==A) and skip the lower-left wave (reconstructed
// from the upper-right wave's col-sums by symmetry).
__global__ __launch_bounds__(256, 4) void sim_kernel() {
    __shared__ __align__(16) unsigned short As[128 * 64];  // [row][k] bf16, swizzled kbytes
    __shared__ __align__(16) unsigned short Bs[128 * 64];
    __shared__ float combuf[512];                          // rowbuf[2][128] + colbuf[2][128]
    __shared__ float ppred[4];

    int lin0 = blockIdx.x;                 // 7056 = 8 * 882
    int xcd = lin0 & 7, slot = lin0 >> 3;  // co-locate each p's tiles on one XCD
    int lin = xcd * 882 + slot;
    int p = lin / 36;
    int t36 = lin - p * 36;
    int trow = TROW36[t36], tcol = TCOL36[t36];
    bool DIAG = (trow == tcol);
    bool PART = (trow < 4) && (tcol == trow + 4);

    int tid = threadIdx.x;
    int wv = tid >> 6, lane = tid & 63;
    int wr = wv >> 1, wc = wv & 1;
    int lr = lane & 15;
    int lk16 = (lane >> 4) * 16;           // byte offset of k-chunk in 128B row
    bool skipw = DIAG && (wv == 2);        // lower-left wave of a diagonal tile

    const char* zb = (const char*)g_Z + (size_t)p * ((size_t)N2B * D_ * 2);
    const char* gA = zb + (size_t)trow * (128 * 512);
    const char* gB = zb + (size_t)tcol * (128 * 512);
    // inverse-swizzled per-lane source offset: lane l -> row l>>3, kbyte ((l&7)^(l>>3))*16
    int lsub = (lane >> 3) * 512 + (((lane & 7) ^ (lane >> 3)) << 4);

    f32x4 acc[4][4];
#pragma unroll
    for (int i = 0; i < 4; ++i)
#pragma unroll
        for (int j = 0; j < 4; ++j)
            acc[i][j] = (f32x4){0.0f, 0.0f, 0.0f, 0.0f};

    const char* BsR = DIAG ? (const char*)As : (const char*)Bs;

    for (int ko = 0; ko < 4; ++ko) {
#pragma unroll
        for (int it = 0; it < 4; ++it) {
            int s = it * 4 + wv;
            int go = s * 4096 + ko * 128 + lsub;
            __builtin_amdgcn_global_load_lds(GLBP(gA + go), LDSP((char*)As + s * 1024), 16, 0, 0);
            if (!DIAG)
                __builtin_amdgcn_global_load_lds(GLBP(gB + go), LDSP((char*)Bs + s * 1024), 16, 0, 0);
        }
        __syncthreads();   // vmcnt(0) drain + barrier
        if (!skipw) {
#pragma unroll
            for (int ks = 0; ks < 2; ++ks) {
                int kswz = (ks * 64 + lk16) ^ ((lr & 7) << 4);   // swizzled read kbyte
                short8 a[4], b[4];
#pragma unroll
                for (int i = 0; i < 4; ++i) {
                    a[i] = *(const short8*)((const char*)As + (wr * 64 + i * 16 + lr) * 128 + kswz);
                    b[i] = *(const short8*)(BsR + (wc * 64 + i * 16 + lr) * 128 + kswz);
                }
#pragma unroll
                for (int i = 0; i < 4; ++i)
#pragma unroll
                    for (int j = 0; j < 4; ++j)
                        acc[i][j] = __builtin_amdgcn_mfma_f32_16x16x32_bf16(a[i], b[j], acc[i][j], 0, 0, 0);
            }
        }
        __syncthreads();
    }

    int wdiag = (wr == wc);
    int r4 = (lane >> 4) * 4;
    float psum[4][4];
    float pcs[4] = {0.0f, 0.0f, 0.0f, 0.0f};
    float pp = 0.0f;
#pragma unroll
    for (int i = 0; i < 4; ++i)
#pragma unroll
        for (int r = 0; r < 4; ++r) psum[i][r] = 0.0f;

    if (!skipw) {
        if (DIAG)      do_epi<1>(acc, psum, pcs, pp, wdiag, lr, r4);
        else if (PART) do_epi<2>(acc, psum, pcs, pp, wdiag, lr, r4);
        else           do_epi<0>(acc, psum, pcs, pp, wdiag, lr, r4);
    }

    float* rowbuf = combuf;         // [wc][128]
    float* colbuf = combuf + 256;   // [wr][128]
    if (!skipw) {
#pragma unroll
        for (int i = 0; i < 4; ++i)
#pragma unroll
            for (int r = 0; r < 4; ++r) {
                float ps = psum[i][r];
                ps += __shfl_xor(ps, 1, 64);
                ps += __shfl_xor(ps, 2, 64);
                ps += __shfl_xor(ps, 4, 64);
                ps += __shfl_xor(ps, 8, 64);
                if (lr == 0) rowbuf[wc * 128 + wr * 64 + i * 16 + r4 + r] = ps;
            }
    }
    if (!DIAG) {
#pragma unroll
        for (int j = 0; j < 4; ++j) {
            float pc = pcs[j];
            pc += __shfl_xor(pc, 16, 64);
            pc += __shfl_xor(pc, 32, 64);
            if (lane < 16) colbuf[wr * 128 + wc * 64 + j * 16 + lane] = pc;
        }
    } else if (wv == 1) {
        // wave (0,1): its col-sums == row-sums of rows 64..127 over cols 0..63
        // (the skipped wave's contribution) -> rowbuf slot [wc=0][64..127]
#pragma unroll
        for (int j = 0; j < 4; ++j) {
            float pc = pcs[j];
            pc += __shfl_xor(pc, 16, 64);
            pc += __shfl_xor(pc, 32, 64);
            if (lane < 16) rowbuf[64 + j * 16 + lane] = pc;
        }
    }
    if (PART) {
        float pw = wave_sum(pp);
        if (lane == 0) ppred[wv] = pw;
    }
    __syncthreads();

    // row-part -> slot tcol (rows trow*128..); col-part -> slot trow (rows tcol*128..)
    if (tid < 128) {
        float v = rowbuf[tid] + rowbuf[128 + tid];
        g_rowps[((size_t)p * 8 + tcol) * N2B + trow * 128 + tid] = v;
    } else if (!DIAG) {
        int x = tid - 128;
        float v = colbuf[x] + colbuf[128 + x];
        g_rowps[((size_t)p * 8 + trow) * N2B + tcol * 128 + x] = v;
    }
    if (PART && tid == 0)
        g_pp2[p * 4 + trow] = 2.0f * (ppred[0] + ppred[1] + ppred[2] + ppred[3]);
}

// ---- Kernel R: per p: sum_rows log(sum of 8 slots) - partner, times meanA
__global__ __launch_bounds__(256) void rowreduce_kernel() {
    int p = blockIdx.x, t = threadIdx.x;
    const float* base = g_rowps + (size_t)p * 8 * N2B;
    float s = 0.0f;
    for (int r = t; r < N2B; r += 256) {
        float S = 0.0f;
#pragma unroll
        for (int k = 0; k < 8; ++k) S += base[(size_t)k * N2B + r];
        s += __logf(S);
    }
    s = wave_sum(s);
    __shared__ float red[4];
    int wv = t >> 6, lane = t & 63;
    if (lane == 0) red[wv] = s;
    __syncthreads();
    if (t == 0) {
        float tot = red[0] + red[1] + red[2] + red[3];
        float pp = g_pp2[p * 4 + 0] + g_pp2[p * 4 + 1] + g_pp2[p * 4 + 2] + g_pp2[p * 4 + 3];
        float ma = 0.0f;
        for (int k = 0; k < 128; ++k) ma += g_mApart[k * P_ + p];
        g_partials[p] = (tot - pp) * (ma * (1.0f / B_));
    }
}

// ---- Kernel F: out = sum_p partials[p] / (2B * P)
__global__ __launch_bounds__(256) void final_kernel(float* __restrict__ out) {
    int t = threadIdx.x;
    float s = (t < P_) ? g_partials[t] : 0.0f;
    s = wave_sum(s);
    __shared__ float red[4];
    int wv = t >> 6, lane = t & 63;
    if (lane == 0) red[wv] = s;
    __syncthreads();
    if (t == 0) out[0] = (red[0] + red[1] + red[2] + red[3]) * (1.0f / ((float)N2B * (float)P_));
}

extern "C" void kernel_launch(void* const* d_in, const int* in_sizes, int n_in,
                              void* d_out, int out_size, void* d_ws, size_t ws_size,
                              hipStream_t stream) {
    const float* gf   = (const float*)d_in[0];   // [512, 256]
    const float* att  = (const float*)d_in[1];   // [512, 8, 14, 14]
    const float* outs = (const float*)d_in[2];   // [512, 256, 14, 14]
    float* out = (float*)d_out;

    hipLaunchKernelGGL(prep12_kernel, dim3(672), dim3(256), 0, stream, gf, att, outs);
    hipLaunchKernelGGL(prep2_kernel, dim3(B_ * 2), dim3(256), 0, stream, outs);
    hipLaunchKernelGGL(sim_kernel, dim3(P_ * 36), dim3(256), 0, stream);
    hipLaunchKernelGGL(rowreduce_kernel, dim3(P_), dim3(256), 0, stream);
    hipLaunchKernelGGL(final_kernel, dim3(1), dim3(256), 0, stream, out);
}